// Round 1
// baseline (1628.021 us; speedup 1.0000x reference)
//
#include <hip/hip_runtime.h>

typedef _Float16 half_t;
typedef __attribute__((ext_vector_type(2))) _Float16 half2_t;

__device__ __forceinline__ half2_t bc2(unsigned int u){ return __builtin_bit_cast(half2_t, u); }
__device__ __forceinline__ float fdot2f(half2_t a, half2_t b, float c){
  return __builtin_amdgcn_fdot2(a, b, c, false);
}
__device__ __forceinline__ float sigmoidf_(float x){ return 1.0f/(1.0f+__expf(-x)); }
__device__ __forceinline__ float tanhf_(float x){ float e=__expf(2.0f*x); return 1.0f - 2.0f/(e+1.0f); }

// GEMV inner loop: weights packed [KC][R][8] f16, x packed half2 in LDS (broadcast reads).
template<int KC, int KSTRIDE>
__device__ __forceinline__ float gemv_row(const half_t* wp, const half_t* xp, float bias){
  float a0=bias, a1=0.f, a2=0.f, a3=0.f;
  #pragma unroll 8
  for (int kc=0; kc<KC; ++kc){
    uint4 w = *reinterpret_cast<const uint4*>(wp + (size_t)kc*KSTRIDE);
    uint4 x = *reinterpret_cast<const uint4*>(xp + kc*8);
    a0 = fdot2f(bc2(w.x), bc2(x.x), a0);
    a1 = fdot2f(bc2(w.y), bc2(x.y), a1);
    a2 = fdot2f(bc2(w.z), bc2(x.z), a2);
    a3 = fdot2f(bc2(w.w), bc2(x.w), a3);
  }
  return (a0+a1)+(a2+a3);
}

// Pack f32 matrix (R x K slice at coloff, row stride ld) -> f16 [K/8][RT][8] at row_off.
__global__ void pack_k(const float* __restrict__ src, half_t* __restrict__ dst,
                       int R, int K, int ld, int coloff, int RT, int row_off){
  int idx = blockIdx.x*blockDim.x + threadIdx.x;
  if (idx >= R*K) return;
  int r = idx / K, k = idx - r*K;
  int kc = k >> 3, j = k & 7;
  dst[((size_t)kc*RT + row_off + r)*8 + j] = (half_t)src[(size_t)r*ld + coloff + k];
}

__launch_bounds__(512, 1)
__global__ void gru_main(
    const float* __restrict__ received,
    const float* __restrict__ Wih0d0, const float* __restrict__ Wih0d1,
    const float* __restrict__ bx0d0, const float* __restrict__ bh0d0,
    const float* __restrict__ bx1d0, const float* __restrict__ bh1d0,
    const float* __restrict__ bx0d1, const float* __restrict__ bh0d1,
    const float* __restrict__ bx1d1, const float* __restrict__ bh1d1,
    const float* __restrict__ vW, const float* __restrict__ fc2b,
    const half_t* __restrict__ W0pack, const half_t* __restrict__ W1pack,
    const half_t* __restrict__ WsPack, const half_t* __restrict__ WhPack,
    const half_t* __restrict__ fc2Pack,
    half_t* __restrict__ o1h, half_t* __restrict__ o2h)
{
  const int dec = blockIdx.x >> 5;
  const int b   = blockIdx.x & 31;
  const int tid = threadIdx.x;

  const float* bx0  = dec ? bx0d1 : bx0d0;
  const float* bh0  = dec ? bh0d1 : bh0d0;
  const float* bx1  = dec ? bx1d1 : bx1d0;
  const float* bh1  = dec ? bh1d1 : bh1d0;
  const float* Wih0 = dec ? Wih0d1 : Wih0d0;
  const half_t* W0  = W0pack + (size_t)dec*49152;   // [16][384][8]
  const half_t* W1  = W1pack + (size_t)dec*98304;   // [16][768][8] rows: 0..383 Wih1(x=h0raw), 384..767 Whh1(h=hatt1)
  half_t* od = dec ? o2h : o1h;

  __shared__ __align__(16) half_t sh_hist[2][128][128];    // raw h history (f16)
  __shared__ __align__(16) half_t sh_histWh[2][128][128];  // hist @ Wh.T, XOR-swizzled rows (f16)
  __shared__ __align__(16) float  sh_hatt[2][128];         // attended carry (f32)
  __shared__ __align__(16) half_t sh_hatt_pk[2][128];
  __shared__ __align__(16) float  sh_hraw[2][128];
  __shared__ __align__(16) half_t sh_hraw_pk[2][128];
  __shared__ __align__(16) float  sh_gx[384];
  __shared__ __align__(16) float  sh_gh[384];
  __shared__ __align__(16) float  sh_g1x[384];
  __shared__ __align__(16) float  sh_g1h[384];
  __shared__ __align__(16) float  sh_sWs[2][128];
  __shared__ __align__(16) float  sh_logits[2][128];
  __shared__ __align__(16) float  sh_probs[2][128];
  __shared__ __align__(16) half_t sh_fc2in[2][256];        // [c | h_raw] packed
  __shared__ __align__(16) float  sh_x[4];
  __shared__ __align__(16) float  sh_vW[128];

  if (tid < 256){ int l=tid>>7, r=tid&127; sh_hatt[l][r]=0.f; sh_hatt_pk[l][r]=(half_t)0.f; }
  if (tid < 128) sh_vW[tid] = vW[tid];
  __syncthreads();

  for (int i=0; i<128; ++i){
    if (tid<3) sh_x[tid] = received[(b*128+i)*3+tid];
    __syncthreads();
    // P1: layer0 gates: gh = Whh0 @ h_att0 + bhh0 ; gx = Wih0 @ x + bih0
    if (tid<384){
      float ax = bx0[tid] + Wih0[tid*3]*sh_x[0] + Wih0[tid*3+1]*sh_x[1] + Wih0[tid*3+2]*sh_x[2];
      float ah = gemv_row<16,3072>(W0 + (size_t)tid*8, &sh_hatt_pk[0][0], bh0[tid]);
      sh_gx[tid]=ax; sh_gh[tid]=ah;
    }
    __syncthreads();
    // P2: layer0 cell
    if (tid<128){
      float rr = sigmoidf_(sh_gx[tid]+sh_gh[tid]);
      float zz = sigmoidf_(sh_gx[128+tid]+sh_gh[128+tid]);
      float nn = tanhf_(sh_gx[256+tid] + rr*sh_gh[256+tid]);
      float h0 = (1.f-zz)*nn + zz*sh_hatt[0][tid];
      sh_hraw[0][tid]=h0;
      half_t hh=(half_t)h0;
      sh_hist[0][i][tid]=hh; sh_hraw_pk[0][tid]=hh; sh_fc2in[0][128+tid]=hh;
    }
    __syncthreads();
    // P3: layer1 gates: 768 rows (gx over h0_raw, gh over h_att1)
    {
      int job=tid;
      bool isX = job<384;
      const half_t* xp = isX ? &sh_hraw_pk[0][0] : &sh_hatt_pk[1][0];
      float bias = isX ? bx1[job] : bh1[job-384];
      float acc = gemv_row<16,6144>(W1 + (size_t)job*8, xp, bias);
      if (isX) sh_g1x[job]=acc; else sh_g1h[job-384]=acc;
      if (tid<256){
        float acc2 = gemv_row<16,6144>(W1 + (size_t)(tid+512)*8, &sh_hatt_pk[1][0], bh1[tid+128]);
        sh_g1h[tid+128]=acc2;
      }
    }
    __syncthreads();
    // P4: layer1 cell + write raw output
    if (tid<128){
      float rr = sigmoidf_(sh_g1x[tid]+sh_g1h[tid]);
      float zz = sigmoidf_(sh_g1x[128+tid]+sh_g1h[128+tid]);
      float nn = tanhf_(sh_g1x[256+tid] + rr*sh_g1h[256+tid]);
      float h1 = (1.f-zz)*nn + zz*sh_hatt[1][tid];
      sh_hraw[1][tid]=h1;
      half_t hh=(half_t)h1;
      sh_hist[1][i][tid]=hh; sh_hraw_pk[1][tid]=hh; sh_fc2in[1][128+tid]=hh;
      od[(size_t)(b*128+i)*128 + tid] = hh;
    }
    __syncthreads();
    // P5: projections: sWs[l] = Ws@h_raw[l]; histWh[l][i] = Wh@h_raw[l] (swizzled)
    {
      int mat = tid>>8, l=(tid>>7)&1, row=tid&127;
      const half_t* wp = (mat ? WhPack : WsPack) + (size_t)row*8;
      float acc = gemv_row<16,1024>(wp, &sh_hraw_pk[l][0], 0.f);
      if (mat==0) sh_sWs[l][row]=acc;
      else {
        int phys = (((row>>1) ^ (i&31))<<1) | (row&1);
        sh_histWh[l][i][phys] = (half_t)acc;
      }
    }
    __syncthreads();
    if (i>0){
      // P6: logits[l][t] = sum_o tanh(sWs+histWh)*v  (2 lanes per (l,t))
      {
        int q=tid&1, t=(tid>>1)&127, l=tid>>8;
        float s=0.f;
        if (t<=i){
          const half_t* hrow = &sh_histWh[l][t][0];
          int tx = t&31;
          #pragma unroll 4
          for (int ji=0; ji<32; ++ji){
            int j = q*32+ji;
            half2_t h2 = *reinterpret_cast<const half2_t*>(hrow + ((j^tx)<<1));
            float2 sv = *reinterpret_cast<const float2*>(&sh_sWs[l][j*2]);
            float2 vv = *reinterpret_cast<const float2*>(&sh_vW[j*2]);
            s += tanhf_(sv.x + (float)h2[0])*vv.x;
            s += tanhf_(sv.y + (float)h2[1])*vv.y;
          }
        }
        s += __shfl_xor(s,1);
        if (q==0 && t<=i) sh_logits[l][t]=s;
      }
      __syncthreads();
      // P7: masked softmax over t<=i (one wave per l)
      if (tid<128){
        int l=tid>>6, lane=tid&63;
        float l0 = (lane<=i)    ? sh_logits[l][lane]    : -3e38f;
        float l1 = (lane+64<=i) ? sh_logits[l][lane+64] : -3e38f;
        float m = fmaxf(l0,l1);
        #pragma unroll
        for (int k=1;k<64;k<<=1) m = fmaxf(m, __shfl_xor(m,k));
        float p0 = (lane<=i)    ? __expf(l0-m) : 0.f;
        float p1 = (lane+64<=i) ? __expf(l1-m) : 0.f;
        float ss = p0+p1;
        #pragma unroll
        for (int k=1;k<64;k<<=1) ss += __shfl_xor(ss,k);
        float inv = 1.f/ss;
        sh_probs[l][lane]=p0*inv; sh_probs[l][lane+64]=p1*inv;
      }
      __syncthreads();
      // P8: context c = sum_t a[t]*hist[t]  (4 lanes per output pair)
      {
        int q=tid&3, o2=(tid>>2)&63, l=tid>>8;
        float c0=0.f,c1=0.f;
        int tend = (q*32+32 < i+1) ? q*32+32 : i+1;
        for (int t=q*32; t<tend; ++t){
          float a = sh_probs[l][t];
          half2_t h2 = *reinterpret_cast<const half2_t*>(&sh_hist[l][t][o2*2]);
          c0 += a*(float)h2[0]; c1 += a*(float)h2[1];
        }
        c0 += __shfl_xor(c0,1); c1 += __shfl_xor(c1,1);
        c0 += __shfl_xor(c0,2); c1 += __shfl_xor(c1,2);
        if (q==0){
          sh_fc2in[l][o2*2]   = (half_t)c0;
          sh_fc2in[l][o2*2+1] = (half_t)c1;
        }
      }
      __syncthreads();
      // P9: h_att[l] = fc2 @ [c|h_raw] + fc2_b
      if (tid<256){
        int l=tid>>7, row=tid&127;
        float acc = gemv_row<32,1024>(fc2Pack + (size_t)row*8, &sh_fc2in[l][0], fc2b[row]);
        sh_hatt[l][row]=acc; sh_hatt_pk[l][row]=(half_t)acc;
      }
    } else {
      if (tid<256){
        int l=tid>>7, row=tid&127;
        float hv = sh_hraw[l][row];
        sh_hatt[l][row]=hv; sh_hatt_pk[l][row]=(half_t)hv;
      }
    }
    __syncthreads();
  }
}

// Final: out[b,t] = sigmoid(tanh(out_W . [o1[b,t] | o2[b,min(t+10,127)]] + out_b))
__global__ void out_kernel(const half_t* __restrict__ o1h, const half_t* __restrict__ o2h,
                           const float* __restrict__ outW, const float* __restrict__ outb,
                           float* __restrict__ dout){
  int tid = blockIdx.x*blockDim.x + threadIdx.x;
  int q = tid&3, job = tid>>2;
  int b = job>>7, t = job&127;
  int t2 = t+10; if (t2>127) t2=127;
  const half_t* r1 = o1h + (size_t)(b*128+t)*128;
  const half_t* r2 = o2h + (size_t)(b*128+t2)*128;
  float acc=0.f;
  for (int j=q*32; j<q*32+32; ++j) acc += outW[j]*(float)r1[j];
  for (int j=q*32; j<q*32+32; ++j) acc += outW[128+j]*(float)r2[j];
  acc += __shfl_xor(acc,1);
  acc += __shfl_xor(acc,2);
  if (q==0){
    float d = tanhf_(acc + outb[0]);
    dout[job] = 1.f/(1.f+__expf(-d));
  }
}

static inline void launch_pack(const void* src, half_t* dst, int R, int K, int ld,
                               int coloff, int RT, int row_off, hipStream_t s){
  int total = R*K;
  pack_k<<<(total+255)/256, 256, 0, s>>>((const float*)src, dst, R, K, ld, coloff, RT, row_off);
}

extern "C" void kernel_launch(void* const* d_in, const int* in_sizes, int n_in,
                              void* d_out, int out_size, void* d_ws, size_t ws_size,
                              hipStream_t stream) {
  const float* received = (const float*)d_in[0];
  const float* Wih1_0 = (const float*)d_in[1];
  const float* Whh1_0 = (const float*)d_in[2];
  const float* bih1_0 = (const float*)d_in[3];
  const float* bhh1_0 = (const float*)d_in[4];
  const float* Wih1_1 = (const float*)d_in[5];
  const float* Whh1_1 = (const float*)d_in[6];
  const float* bih1_1 = (const float*)d_in[7];
  const float* bhh1_1 = (const float*)d_in[8];
  const float* Wih2_0 = (const float*)d_in[9];
  const float* Whh2_0 = (const float*)d_in[10];
  const float* bih2_0 = (const float*)d_in[11];
  const float* bhh2_0 = (const float*)d_in[12];
  const float* Wih2_1 = (const float*)d_in[13];
  const float* Whh2_1 = (const float*)d_in[14];
  const float* bih2_1 = (const float*)d_in[15];
  const float* bhh2_1 = (const float*)d_in[16];
  const float* attn_W = (const float*)d_in[17];
  const float* v_W    = (const float*)d_in[18];
  const float* fc2_W  = (const float*)d_in[19];
  const float* fc2_b  = (const float*)d_in[20];
  const float* out_W  = (const float*)d_in[21];
  const float* out_b  = (const float*)d_in[22];

  half_t* ws = (half_t*)d_ws;
  half_t* W0pack  = ws + 0;        // 2 x [16][384][8] = 98304
  half_t* W1pack  = ws + 98304;    // 2 x [16][768][8] = 196608
  half_t* WsPack  = ws + 294912;   // [16][128][8] = 16384
  half_t* WhPack  = ws + 311296;   // 16384
  half_t* fc2Pack = ws + 327552;   // [32][128][8] = 32768 -> end 360320
  half_t* o1h     = ws + 360448;   // 32*128*128 = 524288
  half_t* o2h     = ws + 884736;   // 524288 -> end 1409024 halves (~2.7 MB)

  // Pack weights to f16 [K/8][R][8]
  launch_pack(Whh1_0, W0pack,          384, 128, 128, 0, 384, 0, stream);
  launch_pack(Whh2_0, W0pack + 49152,  384, 128, 128, 0, 384, 0, stream);
  launch_pack(Wih1_1, W1pack,          384, 128, 128, 0, 768, 0, stream);
  launch_pack(Whh1_1, W1pack,          384, 128, 128, 0, 768, 384, stream);
  launch_pack(Wih2_1, W1pack + 98304,  384, 128, 128, 0, 768, 0, stream);
  launch_pack(Whh2_1, W1pack + 98304,  384, 128, 128, 0, 768, 384, stream);
  launch_pack(attn_W, WsPack,          128, 128, 256, 0,   128, 0, stream);
  launch_pack(attn_W, WhPack,          128, 128, 256, 128, 128, 0, stream);
  launch_pack(fc2_W,  fc2Pack,         128, 256, 256, 0,   128, 0, stream);

  gru_main<<<64, 512, 0, stream>>>(
      received,
      Wih1_0, Wih2_0,
      bih1_0, bhh1_0, bih1_1, bhh1_1,
      bih2_0, bhh2_0, bih2_1, bhh2_1,
      v_W, fc2_b,
      W0pack, W1pack, WsPack, WhPack, fc2Pack,
      o1h, o2h);

  out_kernel<<<64, 256, 0, stream>>>(o1h, o2h, out_W, out_b, (float*)d_out);
}